// Round 17
// baseline (1746.060 us; speedup 1.0000x reference)
//
#include <hip/hip_runtime.h>
#include <string.h>

// ---------------------------------------------------------------------------
// EnhancedRPTModel: MoE(top-2 routed) + memory-augmented attention + 3-step
// gated reasoning + integration.  bf16 MFMA 16x16x32.
// GEMM engine (R9-proven): 128x128x64, 8 waves, dbuf 64KB LDS (2 blocks/CU).
// R17: k_fa v2 — Q in registers (loop-invariant), double-buffered K/V tiles
// (stage issued a full iteration ahead; vmcnt(0) waits on hidden loads),
// QK^T split into two accumulator chains.  Math identical to R16 (verified).
// ---------------------------------------------------------------------------

typedef __attribute__((ext_vector_type(4))) float f32x4;
typedef __attribute__((ext_vector_type(8))) __bf16 bf16x8;

#define NTOK 4096            // B*S
#define HDIM 2048
#define AS1 __attribute__((address_space(1)))
#define AS3 __attribute__((address_space(3)))

// ---------------- small helpers ----------------
__device__ __forceinline__ unsigned short f2bf(float f) {
  unsigned u = __float_as_uint(f);
  unsigned r = (u + 0x7fffu + ((u >> 16) & 1u)) >> 16;   // RNE
  return (unsigned short)r;
}
__device__ __forceinline__ float bf2f(unsigned short u) {
  return __uint_as_float(((unsigned)u) << 16);
}
__device__ __forceinline__ void unpack8(uint4 r, float* v) {
  v[0]=bf2f((unsigned short)(r.x&0xffff)); v[1]=bf2f((unsigned short)(r.x>>16));
  v[2]=bf2f((unsigned short)(r.y&0xffff)); v[3]=bf2f((unsigned short)(r.y>>16));
  v[4]=bf2f((unsigned short)(r.z&0xffff)); v[5]=bf2f((unsigned short)(r.z>>16));
  v[6]=bf2f((unsigned short)(r.w&0xffff)); v[7]=bf2f((unsigned short)(r.w>>16));
}
__device__ __forceinline__ uint4 pack8(const float* v) {
  uint4 r;
  r.x = (unsigned)f2bf(v[0]) | ((unsigned)f2bf(v[1])<<16);
  r.y = (unsigned)f2bf(v[2]) | ((unsigned)f2bf(v[3])<<16);
  r.z = (unsigned)f2bf(v[4]) | ((unsigned)f2bf(v[5])<<16);
  r.w = (unsigned)f2bf(v[6]) | ((unsigned)f2bf(v[7])<<16);
  return r;
}

// ---------------- conversion / transpose kernels ----------------
__global__ void k_tconv(const float* __restrict__ in, unsigned short* __restrict__ out,
                        int R, int C, long inB, long outB) {
  __shared__ float tl[32][33];
  const int z = blockIdx.z;
  const float* ip = in + (long)z * inB;
  unsigned short* op = out + (long)z * outB;
  const int tx = threadIdx.x & 31, ty = threadIdx.x >> 5;
  const int c0 = blockIdx.x * 32, r0 = blockIdx.y * 32;
#pragma unroll
  for (int i = 0; i < 4; i++)
    tl[ty + i*8][tx] = ip[(long)(r0 + ty + i*8) * C + c0 + tx];
  __syncthreads();
#pragma unroll
  for (int i = 0; i < 4; i++)
    op[(long)(c0 + ty + i*8) * R + r0 + tx] = f2bf(tl[tx][ty + i*8]);
}

// 4 square 2048x2048 transposes (q_w,k_w,v_w -> slots 0..2; o_w -> after MAT)
__global__ void k_tconv4(const float* __restrict__ i0, const float* __restrict__ i1,
                         const float* __restrict__ i2, const float* __restrict__ i3,
                         unsigned short* __restrict__ out) {
  __shared__ float tl[32][33];
  const int z = blockIdx.z;
  const float* ip = (z == 0) ? i0 : (z == 1) ? i1 : (z == 2) ? i2 : i3;
  unsigned short* op = out + ((z < 3) ? (size_t)z * 2048 * 2048 : (size_t)6400 * 2048);
  const int tx = threadIdx.x & 31, ty = threadIdx.x >> 5;
  const int c0 = blockIdx.x * 32, r0 = blockIdx.y * 32;
#pragma unroll
  for (int i = 0; i < 4; i++)
    tl[ty + i*8][tx] = ip[(long)(r0 + ty + i*8) * 2048 + c0 + tx];
  __syncthreads();
#pragma unroll
  for (int i = 0; i < 4; i++)
    op[(long)(c0 + ty + i*8) * 2048 + r0 + tx] = f2bf(tl[tx][ty + i*8]);
}

// V slice of interleaved qkvm [4096][6400] -> per-(b,h) [256][2048] (d-major)
__global__ void k_tvact(const unsigned short* __restrict__ qkv, unsigned short* __restrict__ vT) {
  __shared__ unsigned short tl[32][33];
  const int z = blockIdx.z, b = z >> 3, hh = z & 7;
  const unsigned short* ip = qkv + (long)b * 2048 * 6400 + 4096 + hh * 256;
  unsigned short* op = vT + (long)z * 256 * 2048;
  const int tx = threadIdx.x & 31, ty = threadIdx.x >> 5;
  const int d0 = blockIdx.x * 32, s0 = blockIdx.y * 32;
#pragma unroll
  for (int i = 0; i < 4; i++)
    tl[ty + i*8][tx] = ip[(long)(s0 + ty + i*8) * 6400 + d0 + tx];
  __syncthreads();
#pragma unroll
  for (int i = 0; i < 4; i++)
    op[(long)(d0 + ty + i*8) * 2048 + s0 + tx] = tl[tx][ty + i*8];
}

// merged small setup: mask vector, qkv|mattn bias concat (6400), rs|hg bias, meta
__global__ void k_misc(const float* __restrict__ mask, float* __restrict__ mv,
                       const float* __restrict__ qb, const float* __restrict__ kb,
                       const float* __restrict__ vb, const float* __restrict__ mb,
                       float* __restrict__ qkvb,
                       const float* __restrict__ rsb1, const float* __restrict__ hgb1,
                       float* __restrict__ rhb, int* __restrict__ meta) {
  const int b = blockIdx.x, t = threadIdx.x;
  if (b < 16) {
    int i = b * 256 + t; mv[i] = -1e9f * mask[i];
  } else if (b < 41) {
    int i = (b - 16) * 256 + t;                         // 0..6399
    if (i < 6400)
      qkvb[i] = (i < 2048) ? qb[i] : (i < 4096) ? kb[i - 2048]
              : (i < 6144) ? vb[i - 4096] : mb[i - 6144];
  } else if (b < 47) {
    int i = (b - 41) * 256 + t;                         // 0..1535
    int s = i >> 9, c = i & 511;
    rhb[s * 1024 + c] = rsb1[i]; rhb[s * 1024 + 512 + c] = hgb1[i];
  } else {
    if (t < 8) meta[t] = 0;
  }
}

// ---------------- routing (h->bf16 conversion fused in) ----------------
__global__ void k_gate(const float* __restrict__ x, const float* __restrict__ gw,
                       const float* __restrict__ gb, int* __restrict__ meta,
                       int* __restrict__ e0a, int* __restrict__ e1a,
                       float* __restrict__ w0a, float* __restrict__ w1a,
                       unsigned short* __restrict__ xb) {
  const int wv = threadIdx.x >> 6, ln = threadIdx.x & 63;
  const int n = blockIdx.x * 4 + wv;
  const float* xr = x + (long)n * HDIM;
  unsigned short* xo = xb + (long)n * HDIM;
  float s[8] = {0,0,0,0,0,0,0,0};
  for (int k = ln; k < HDIM; k += 64) {
    float xv = xr[k];
    xo[k] = f2bf(xv);
    const float* g = gw + (long)k * 8;
#pragma unroll
    for (int e = 0; e < 8; e++) s[e] += xv * g[e];
  }
#pragma unroll
  for (int e = 0; e < 8; e++)
    for (int d = 32; d; d >>= 1) s[e] += __shfl_xor(s[e], d);
  if (ln == 0) {
    float mx = -1e30f;
#pragma unroll
    for (int e = 0; e < 8; e++) { s[e] += gb[e]; mx = fmaxf(mx, s[e]); }
    float p[8], sum = 0.f;
#pragma unroll
    for (int e = 0; e < 8; e++) { p[e] = expf(s[e] - mx); sum += p[e]; }
    float inv = 1.f / sum;
#pragma unroll
    for (int e = 0; e < 8; e++) p[e] *= inv;
    int e0 = 0;
    for (int e = 1; e < 8; e++) if (p[e] > p[e0]) e0 = e;
    int e1 = (e0 == 0) ? 1 : 0;
    for (int e = 0; e < 8; e++) if (e != e0 && p[e] > p[e1]) e1 = e;
    float q = expf(p[e1] - p[e0]);
    float w0 = 1.f / (1.f + q), w1 = q / (1.f + q);
    e0a[n] = e0; e1a[n] = e1; w0a[n] = w0; w1a[n] = w1;
    atomicAdd(&meta[e0], 1); atomicAdd(&meta[e1], 1);
  }
}

__global__ void k_buildmap(int* meta) {        // 128-row tiles
  if (threadIdx.x == 0 && blockIdx.x == 0) {
    int cum = 0, nT = 0;
    for (int e = 0; e < 8; e++) {
      int c = meta[e];
      meta[16 + e] = cum; meta[24 + e] = cum + c; meta[8 + e] = 0;
      int t = (c + 127) >> 7;
      for (int i = 0; i < t; i++) { meta[33 + nT] = e; meta[129 + nT] = cum + i * 128; nT++; }
      cum += c;
    }
    meta[32] = nT;
  }
}

__global__ void k_scatter(int* __restrict__ meta, const int* __restrict__ e0a,
                          const int* __restrict__ e1a, int* __restrict__ s0a,
                          int* __restrict__ s1a, int* __restrict__ srcTok) {
  const int n = blockIdx.x * 256 + threadIdx.x;
  if (n < NTOK) {
    int e0 = e0a[n], e1 = e1a[n];
    int s0 = meta[16 + e0] + atomicAdd(&meta[8 + e0], 1);
    int s1 = meta[16 + e1] + atomicAdd(&meta[8 + e1], 1);
    s0a[n] = s0; s1a[n] = s1; srcTok[s0] = n; srcTok[s1] = n;
  }
}

__global__ void k_combine(const float* __restrict__ h, const unsigned short* __restrict__ eo,
                          const int* __restrict__ s0a, const int* __restrict__ s1a,
                          const float* __restrict__ w0a, const float* __restrict__ w1a,
                          unsigned short* __restrict__ h2b) {
  const int n = blockIdx.x, c = threadIdx.x * 8;
  const float w0 = w0a[n], w1 = w1a[n];
  uint4 a = *(const uint4*)(eo + (long)s0a[n] * HDIM + c);
  uint4 b = *(const uint4*)(eo + (long)s1a[n] * HDIM + c);
  float va[8], vb[8]; unpack8(a, va); unpack8(b, vb);
  const float* hr = h + (long)n * HDIM + c;
  float o[8];
#pragma unroll
  for (int j = 0; j < 8; j++) o[j] = hr[j] + 0.5f * (w0 * va[j] + w1 * vb[j]);
  *(uint4*)(h2b + (long)n * HDIM + c) = pack8(o);
}

// ---------------- softmax (memory attention, 256 wide, bf16 strided in) ----
__global__ void k_softmax256(const unsigned short* __restrict__ in, long ld,
                             unsigned short* __restrict__ out) {
  const int wv = threadIdx.x >> 6, ln = threadIdx.x & 63;
  const long r = (long)blockIdx.x * 4 + wv;
  uint2 raw = ((const uint2*)(in + r * ld))[ln];
  float v[4];
  v[0]=bf2f((unsigned short)(raw.x&0xffff)); v[1]=bf2f((unsigned short)(raw.x>>16));
  v[2]=bf2f((unsigned short)(raw.y&0xffff)); v[3]=bf2f((unsigned short)(raw.y>>16));
  float m = fmaxf(fmaxf(v[0], v[1]), fmaxf(v[2], v[3]));
  for (int d = 32; d; d >>= 1) m = fmaxf(m, __shfl_xor(m, d));
  float s = 0.f;
#pragma unroll
  for (int j = 0; j < 4; j++) { v[j] = expf(v[j] - m); s += v[j]; }
  for (int d = 32; d; d >>= 1) s += __shfl_xor(s, d);
  const float inv = 1.f / s;
  union { unsigned short u[4]; uint2 d2; } p;
#pragma unroll
  for (int j = 0; j < 4; j++) p.u[j] = f2bf(v[j] * inv);
  ((uint2*)(out + r * 256))[ln] = p.d2;
}

// ---------------- reasoning helpers ----------------
__global__ void k_gdot(const unsigned short* __restrict__ g1, long ld, const float* __restrict__ w,
                       const float* __restrict__ bb, float* __restrict__ gv) {
  const int wv = threadIdx.x >> 6, ln = threadIdx.x & 63;
  const int n = blockIdx.x * 4 + wv;
  uint4 raw = *(const uint4*)(g1 + (long)n * ld + ln * 8);
  float v[8]; unpack8(raw, v);
  const float4 wa = ((const float4*)w)[ln * 2];
  const float4 wb = ((const float4*)w)[ln * 2 + 1];
  float s = v[0]*wa.x + v[1]*wa.y + v[2]*wa.z + v[3]*wa.w
          + v[4]*wb.x + v[5]*wb.y + v[6]*wb.z + v[7]*wb.w;
  for (int d = 32; d; d >>= 1) s += __shfl_xor(s, d);
  if (ln == 0) gv[n] = 1.f / (1.f + expf(-(s + bb[0])));
}

__global__ void k_lnupdate(const unsigned short* __restrict__ so,
                           const unsigned short* __restrict__ curIn,
                           const float* __restrict__ gv, const float* __restrict__ lng,
                           const float* __restrict__ lnb,
                           unsigned short* __restrict__ curbOut,
                           unsigned short* __restrict__ outs, int step) {
  const int n = blockIdx.x, t = threadIdx.x, wv = t >> 6, ln = t & 63, c = t * 8;
  uint4 raw = *(const uint4*)(so + (long)n * 2048 + c);
  float x[8]; unpack8(raw, x);
  float s1 = 0.f, s2 = 0.f;
#pragma unroll
  for (int j = 0; j < 8; j++) { s1 += x[j]; s2 += x[j] * x[j]; }
  for (int d = 32; d; d >>= 1) { s1 += __shfl_xor(s1, d); s2 += __shfl_xor(s2, d); }
  __shared__ float a1[4], a2[4];
  if (ln == 0) { a1[wv] = s1; a2[wv] = s2; }
  __syncthreads();
  s1 = a1[0] + a1[1] + a1[2] + a1[3];
  s2 = a2[0] + a2[1] + a2[2] + a2[3];
  const float mean = s1 * (1.f / 2048.f);
  const float var = s2 * (1.f / 2048.f) - mean * mean;
  const float rstd = rsqrtf(var + 1e-5f);
  const float g = gv[n];
  uint4 ci = *(const uint4*)(curIn + (long)n * 2048 + c);
  float cv[8]; unpack8(ci, cv);
  float o[8];
#pragma unroll
  for (int j = 0; j < 8; j++) {
    float l = (x[j] - mean) * rstd * lng[c + j] + lnb[c + j];
    o[j] = cv[j] + g * l;
  }
  const uint4 pk = pack8(o);
  *(uint4*)(curbOut + (long)n * 2048 + c) = pk;
  *(uint4*)(outs + (long)n * 6144 + (long)step * 2048 + c) = pk;
}

// ---------------- GEMM argument block ----------------
struct GArgs {
  const unsigned short* A; long lda, aSO, aSI;
  const unsigned short* Bt; long ldb, bSO, bSI;
  int M, N, K;
  const float* adv; long advSO, advSI;   // per-col addend (bias / -1e9*mask)
  float alpha, rscale;
  const float* rF; long ldrF, rfSO, rfSI;
  const unsigned short* rB; long ldrB, rbSO, rbSI;
  float* oF; long ldoF, ofSO, ofSI;
  unsigned short* oB; long ldoB, obSO, obSI;
  const int* meta;                        // MOE tile map
  const int* srcTok;                      // MOE==2: slot -> token row in A
};

// =============== 128x128x64 dbuf GEMM, 8 waves (2M x 4N) ====================
template <int MOE, int RELU, int RESID, int OUTF, int OUTB>
__global__ __launch_bounds__(512) void gemm_bt(GArgs g) {
  __shared__ unsigned short lds[2 * 16384];   // 64 KB
  const int t = threadIdx.x, wv = t >> 6, ln = t & 63, ln15 = ln & 15;
  const int lr8 = ln >> 3;
  const int lsl = (ln & 7) ^ lr8;             // pre-swizzled k-slot (rule #21)
  const int bz = blockIdx.z;
  int row0, rowMax;
  const unsigned short *A, *Bt;
  long advO = 0, rFO = 0, rBO = 0, oFO = 0, oBO = 0;
  if constexpr (MOE) {
    const int ty = blockIdx.y;
    if (ty >= g.meta[32]) return;
    const int e = g.meta[33 + ty];
    row0 = g.meta[129 + ty]; rowMax = g.meta[24 + e];
    A = g.A; Bt = g.Bt + (long)e * g.bSO;
    advO = (long)e * g.advSO;
  } else {
    row0 = blockIdx.y << 7; rowMax = g.M;
    const long bo = (long)(bz >> 3), bi = (long)(bz & 7);
    A = g.A + bo * g.aSO + bi * g.aSI;
    Bt = g.Bt + bo * g.bSO + bi * g.bSI;
    advO = bo * g.advSO + bi * g.advSI;
    rFO = bo * g.rfSO + bi * g.rfSI;
    rBO = bo * g.rbSO + bi * g.rbSI;
    oFO = bo * g.ofSO + bi * g.ofSI;
    oBO = bo * g.obSO + bi * g.obSI;
  }
  const int col0 = blockIdx.x << 7;
  const long lda = g.lda, ldb = g.ldb;
  const int wm = (wv >> 2) << 6;              // 0 / 64
  const int wc = (wv & 3) << 5;               // 0,32,64,96

  int grow0, grow1;
  {
    int r0i = row0 + (wv << 4) + lr8;
    int r1i = r0i + 8;
    if constexpr (MOE) {
      r0i = (r0i < rowMax) ? r0i : (rowMax - 1);
      r1i = (r1i < rowMax) ? r1i : (rowMax - 1);
    }
    if constexpr (MOE == 2) { grow0 = g.srcTok[r0i]; grow1 = g.srcTok[r1i]; }
    else { grow0 = r0i; grow1 = r1i; }
  }

  auto STAGE = [&](int kt, unsigned base) {
    const long kk = ((long)kt << 6) + (lsl << 3);
    {
      const int rb = (wv << 4);
      __builtin_amdgcn_global_load_lds(
          (const AS1 void*)(A + (long)grow0 * lda + kk),
          (AS3 void*)(lds + base + (rb << 6)), 16, 0, 0);
      __builtin_amdgcn_global_load_lds(
          (const AS1 void*)(A + (long)grow1 * lda + kk),
          (AS3 void*)(lds + base + ((rb + 8) << 6)), 16, 0, 0);
    }
#pragma unroll
    for (int l = 0; l < 2; ++l) {
      const int rb = (wv << 4) + (l << 3);
      __builtin_amdgcn_global_load_lds(
          (const AS1 void*)(Bt + (long)(col0 + rb + lr8) * ldb + kk),
          (AS3 void*)(lds + base + 8192 + (rb << 6)), 16, 0, 0);
    }
  };

  const f32x4 fz = {0.f, 0.f, 0.f, 0.f};
  f32x4 acc[4][2];
#pragma unroll
  for (int i = 0; i < 4; i++)
#pragma unroll
    for (int j = 0; j < 2; j++) acc[i][j] = fz;

  const int nt = g.K >> 6;

  STAGE(0, 0);
  asm volatile("s_waitcnt vmcnt(0)" ::: "memory");
  __builtin_amdgcn_s_barrier();

  for (int kt = 0; kt < nt; ++kt) {
    const unsigned aB = (kt & 1) ? 16384u : 0u;
    const unsigned nB = aB ^ 16384u;
    if (kt + 1 < nt) STAGE(kt + 1, nB);
#pragma unroll
    for (int ks = 0; ks < 2; ++ks) {
      const int kb = (ks << 2) + (ln >> 4);
      bf16x8 bg[2];
#pragma unroll
      for (int j = 0; j < 2; ++j) {
        const int r = wc + (j << 4) + ln15;
        bg[j] = *(const bf16x8*)(lds + aB + 8192 + (r << 6) + ((kb ^ (r & 7)) << 3));
      }
      __builtin_amdgcn_s_setprio(1);
#pragma unroll
      for (int i = 0; i < 4; ++i) {
        const int r = wm + (i << 4) + ln15;
        bf16x8 a = *(const bf16x8*)(lds + aB + (r << 6) + ((kb ^ (r & 7)) << 3));
#pragma unroll
        for (int j = 0; j < 2; ++j)
          acc[i][j] = __builtin_amdgcn_mfma_f32_16x16x32_bf16(a, bg[j], acc[i][j], 0, 0, 0);
      }
      __builtin_amdgcn_s_setprio(0);
    }
    asm volatile("s_waitcnt vmcnt(0)" ::: "memory");
    __builtin_amdgcn_s_barrier();
  }

#pragma unroll
  for (int i = 0; i < 4; i++) {
#pragma unroll
    for (int j = 0; j < 2; j++) {
      const int cc = col0 + wc + (j << 4) + ln15;
      const float av = g.adv ? g.adv[advO + cc] : 0.f;
#pragma unroll
      for (int r = 0; r < 4; r++) {
        const int rr = row0 + wm + (i << 4) + ((ln >> 4) << 2) + r;
        if (rr < rowMax) {
          float v = g.alpha * acc[i][j][r] + av;
          if constexpr (RELU) v = fmaxf(v, 0.f);
          if constexpr (RESID == 1) v = g.rF[rFO + (long)rr * g.ldrF + cc] + g.rscale * v;
          if constexpr (RESID == 2) v = bf2f(g.rB[rBO + (long)rr * g.ldrB + cc]) + g.rscale * v;
          if constexpr (OUTF) g.oF[oFO + (long)rr * g.ldoF + cc] = v;
          if constexpr (OUTB) g.oB[oBO + (long)rr * g.ldoB + cc] = f2bf(v);
        }
      }
    }
  }
}

// ================= flash attention v2: O = softmax(QK^T/16 + mask) V =======
// Block: 64 q-rows x full head (d=256), grid (32 qtiles, 16 bh), 512 thr.
// KVBLK=32, 64 iterations.  Q in registers (32 VGPR).  K/V double-buffered:
// stage(kt+1) issues at iteration top, vmcnt(0) at bottom waits on loads that
// flew under the whole compute phase.  QK^T uses two accumulator chains.
// LDS: Ks[2][8192] | Vts[2][8192] | Ps[2048] ushorts + mask/stats ≈ 79.9KB.
__global__ __launch_bounds__(512) void k_fa(const unsigned short* __restrict__ qkvm,
                                            const unsigned short* __restrict__ Vt,
                                            const float* __restrict__ msk,
                                            unsigned short* __restrict__ O) {
  __shared__ unsigned short sm[34816];   // Ks[2]@0, Vts[2]@16384, Ps@32768
  __shared__ float msk_s[2048];
  __shared__ float m_run[64], l_run[64], fac[64], mnv[64], tsm[128], tss[128];
  const int t = threadIdx.x, wv = t >> 6, ln = t & 63, ln15 = ln & 15;
  const int rt = blockIdx.x, bh = blockIdx.y;
  const int b = bh >> 3, hh = bh & 7;
  const int q0 = rt << 6;
  const unsigned short* Bq = qkvm + (long)b * 2048 * 6400;

  const int rw = wv >> 1, cw = wv & 1;         // QK frag coords
  const int wc = wv << 5;                      // PV: this wave's 32 d-cols
  const int rowbase = (rw << 4) + ((ln >> 4) << 2);
  const int ra = (rw << 4) + ln15;

  // ---- Q fragments in registers (loop-invariant): 8 x bf16x8 ----
  bf16x8 qreg[8];
#pragma unroll
  for (int ks = 0; ks < 8; ++ks)
    qreg[ks] = *(const bf16x8*)(Bq + (long)(q0 + ra) * 6400 + hh * 256 + ks * 32 + ((ln >> 4) << 3));

  // mask preload + stats init
#pragma unroll
  for (int l = 0; l < 4; ++l) {
    const int i = l * 512 + t;
    msk_s[i] = msk[b * 2048 + i];
  }
  if (t < 64) { m_run[t] = -3.0e38f; l_run[t] = 0.f; }

  auto STAGEKV = [&](int kt, int buf) {
#pragma unroll
    for (int l = 0; l < 2; ++l) {              // K tile 32x256 (4 panels [32][64])
      const int li = l * 512 + t;
      const int p = li >> 8, r = (li >> 3) & 31, s = li & 7;
      __builtin_amdgcn_global_load_lds(
          (const AS1 void*)(Bq + (long)(kt * 32 + r) * 6400 + 2048 + hh * 256 + p * 64 + ((s ^ (r & 7)) << 3)),
          (AS3 void*)(sm + buf * 8192 + li * 8), 16, 0, 0);
    }
#pragma unroll
    for (int l = 0; l < 2; ++l) {              // Vt tile 256x32
      const int li = l * 512 + t;
      const int r = li >> 2, s = li & 3;
      __builtin_amdgcn_global_load_lds(
          (const AS1 void*)(Vt + (long)bh * 524288 + (long)r * 2048 + kt * 32 + ((s ^ ((r >> 1) & 3)) << 3)),
          (AS3 void*)(sm + 16384 + buf * 8192 + li * 8), 16, 0, 0);
    }
  };
  STAGEKV(0, 0);
  asm volatile("s_waitcnt vmcnt(0)" ::: "memory");
  __syncthreads();

  const f32x4 fz = {0.f, 0.f, 0.f, 0.f};
  f32x4 acc[4][2];
#pragma unroll
  for (int i = 0; i < 4; i++)
#pragma unroll
    for (int j = 0; j < 2; j++) acc[i][j] = fz;

  for (int kt = 0; kt < 64; ++kt) {
    const int cur = kt & 1;
    if (kt + 1 < 64) STAGEKV(kt + 1, cur ^ 1);
    // ---- QK^T: two accumulator chains, K frag from Ks[cur] ----
    f32x4 sA = fz, sB = fz;
#pragma unroll
    for (int ks = 0; ks < 8; ++ks) {
      const int kp = ks >> 1;
      const int kb = ((ks & 1) << 2) + (ln >> 4);
      const int rb = (cw << 4) + ln15;
      bf16x8 bb = *(const bf16x8*)(sm + cur * 8192 + kp * 2048 + (rb << 6) + ((kb ^ (rb & 7)) << 3));
      if (ks & 1) sB = __builtin_amdgcn_mfma_f32_16x16x32_bf16(qreg[ks], bb, sB, 0, 0, 0);
      else        sA = __builtin_amdgcn_mfma_f32_16x16x32_bf16(qreg[ks], bb, sA, 0, 0, 0);
    }
    // scale + mask + per-frag row max
    float sv[4];
    const float mk = msk_s[(kt << 5) + (cw << 4) + ln15];
#pragma unroll
    for (int r = 0; r < 4; ++r) {
      sv[r] = (sA[r] + sB[r]) * 0.0625f + mk;
      float mr = sv[r];
#pragma unroll
      for (int d = 1; d < 16; d <<= 1) mr = fmaxf(mr, __shfl_xor(mr, d));
      if (ln15 == 0) tsm[((rowbase + r) << 1) + cw] = mr;
    }
    __syncthreads();
    if (t < 64) {
      if (kt > 0) l_run[t] = l_run[t] * fac[t] + tss[t << 1] + tss[(t << 1) + 1];
      const float mt = fmaxf(tsm[t << 1], tsm[(t << 1) + 1]);
      const float mn = fmaxf(m_run[t], mt);
      fac[t] = expf(m_run[t] - mn);
      mnv[t] = mn; m_run[t] = mn;
    }
    __syncthreads();
    // ---- P = exp(S - m), write Ps, row sums; rescale acc ----
#pragma unroll
    for (int r = 0; r < 4; ++r) {
      const int row = rowbase + r;
      const float p = expf(sv[r] - mnv[row]);
      const int col = (cw << 4) + ln15;
      sm[32768 + (row << 5) + (((col >> 3) ^ ((row >> 1) & 3)) << 3) + (col & 7)] = f2bf(p);
      float sr = p;
#pragma unroll
      for (int d = 1; d < 16; d <<= 1) sr += __shfl_xor(sr, d);
      if (ln15 == 0) tss[(row << 1) + cw] = sr;
    }
#pragma unroll
    for (int i = 0; i < 4; ++i) {
      const int rw2 = (i << 4) + ((ln >> 4) << 2);
#pragma unroll
      for (int r = 0; r < 4; ++r) {
        const float fv = fac[rw2 + r];
        acc[i][0][r] *= fv; acc[i][1][r] *= fv;
      }
    }
    __syncthreads();
    // ---- PV: O += P(64x32) @ V(32x256) from Vts[cur] ----
    const int kb2 = ln >> 4;
#pragma unroll
    for (int i = 0; i < 4; ++i) {
      const int rp = (i << 4) + ln15;
      bf16x8 a = *(const bf16x8*)(sm + 32768 + (rp << 5) + ((kb2 ^ ((rp >> 1) & 3)) << 3));
#pragma unroll
      for (int j = 0; j < 2; ++j) {
        const int rv = wc + (j << 4) + ln15;
        bf16x8 bv = *(const bf16x8*)(sm + 16384 + cur * 8192 + (rv << 5) + ((kb2 ^ ((rv >> 1) & 3)) << 3));
        acc[i][j] = __builtin_amdgcn_mfma_f32_16x16x32_bf16(a, bv, acc[i][j], 0, 0, 0);
      }
    }
    asm volatile("s_waitcnt vmcnt(0)" ::: "memory");   // next tile landed (hidden)
    __syncthreads();
  }
  // final l update + inverse
  if (t < 64) {
    const float l = l_run[t] * fac[t] + tss[t << 1] + tss[(t << 1) + 1];
    fac[t] = 1.f / l;
  }
  __syncthreads();
  // epilogue
  unsigned short* Ob = O + (long)b * 2048 * 2048 + hh * 256;
#pragma unroll
  for (int i = 0; i < 4; ++i) {
#pragma unroll
    for (int j = 0; j < 2; ++j) {
      const int cc = wc + (j << 4) + ln15;
#pragma unroll
      for (int r = 0; r < 4; ++r) {
        const int row = (i << 4) + ((ln >> 4) << 2) + r;
        Ob[(long)(q0 + row) * 2048 + cc] = f2bf(acc[i][j][r] * fac[row]);
      }
    }
  }
}

// ---------------- workspace layout (bytes) ----------------
static constexpr size_t O_W1T = 0;                                        // [8][4096][2048] bf16
static constexpr size_t O_W2T = O_W1T + (size_t)8 * 4096 * 2048 * 2;      // [8][2048][4096] bf16
static constexpr size_t O_QT  = O_W2T + (size_t)8 * 4096 * 2048 * 2;      // [6400+2048][2048] = Q|K|V|MAT|O
static constexpr size_t O_OT  = O_QT + (size_t)6400 * 2048 * 2;           // o_w^T inside QT block
static constexpr size_t O_MPT = O_QT + (size_t)8448 * 2048 * 2;           // [2048][512]
static constexpr size_t O_MVT = O_MPT + (size_t)2048 * 512 * 2;           // [512][256]
static constexpr size_t O_RH1 = O_MVT + (size_t)512 * 256 * 2;            // [3][1024][2048] rs|hg
static constexpr size_t O_RS2 = O_RH1 + (size_t)3 * 1024 * 2048 * 2;      // [3][2048][512]
static constexpr size_t O_IGT = O_RS2 + (size_t)3 * 2048 * 512 * 2;       // [2048][6144]
static constexpr size_t O_META= O_IGT + (size_t)2048 * 6144 * 2;          // 4KB ints
static constexpr size_t O_E0  = O_META + 4096;
static constexpr size_t O_E1  = O_E0 + 16384;
static constexpr size_t O_W0  = O_E1 + 16384;
static constexpr size_t O_W1  = O_W0 + 16384;
static constexpr size_t O_S0  = O_W1 + 16384;
static constexpr size_t O_S1  = O_S0 + 16384;
static constexpr size_t O_SRC = O_S1 + 16384;                             // 8192 ints
static constexpr size_t O_MSK = O_SRC + 32768;
static constexpr size_t O_GV  = O_MSK + 16384;
static constexpr size_t O_QKVB= O_GV + 16384;                             // 6400 f32
static constexpr size_t O_RHB = O_QKVB + 6400 * 4;                        // 3072 f32
static constexpr size_t O_H2B = O_RHB + 3072 * 4;                         // bf16 [4096][2048]
static constexpr size_t O_H3B = O_H2B + (size_t)4096 * 2048 * 2;
static constexpr size_t O_ATT = O_H3B + (size_t)4096 * 2048 * 2;          // attnb bf16
static constexpr size_t O_AO2 = O_ATT + (size_t)4096 * 2048 * 2;
static constexpr size_t O_MPB = O_AO2 + (size_t)4096 * 2048 * 2;
static constexpr size_t O_MPV = O_MPB + (size_t)4096 * 256 * 2;
static constexpr size_t O_AR  = O_MPV + (size_t)4096 * 512 * 2;           // phase arena
// MoE phase
static constexpr size_t O_XB = O_AR;
static constexpr size_t O_H1 = O_XB + (size_t)4096 * 2048 * 2 + (size_t)8192 * 2048 * 2;
static constexpr size_t O_EO = O_H1 + (size_t)8192 * 4096 * 2;
// attention phase (aliases tail of MoE arena beyond XB): qkvm [4096][6400]
static constexpr size_t O_QB = O_XB + (size_t)4096 * 2048 * 2;
static constexpr size_t O_VT = O_QB + (size_t)4096 * 6400 * 2;
// reasoning phase (aliases arena)
static constexpr size_t O_T1 = O_QB;
static constexpr size_t O_SOB= O_T1 + (size_t)4096 * 1024 * 2;            // bf16 [4096][2048]
static constexpr size_t O_CRB= O_SOB + (size_t)4096 * 2048 * 2;
static constexpr size_t O_OUS= O_CRB + (size_t)4096 * 2048 * 2;

extern "C" void kernel_launch(void* const* d_in, const int* in_sizes, int n_in,
                              void* d_out, int out_size, void* d_ws, size_t ws_size,
                              hipStream_t stream) {
  (void)in_sizes; (void)n_in; (void)out_size; (void)ws_size;
  const float* h        = (const float*)d_in[0];
  const float* mask     = (const float*)d_in[1];
  const float* gate_w   = (const float*)d_in[2];
  const float* gate_b   = (const float*)d_in[3];
  const float* moe_w1   = (const float*)d_in[4];
  const float* moe_b1   = (const float*)d_in[5];
  const float* moe_w2   = (const float*)d_in[6];
  const float* moe_b2   = (const float*)d_in[7];
  const float* q_w      = (const float*)d_in[8];
  const float* q_b      = (const float*)d_in[9];
  const float* k_w      = (const float*)d_in[10];
  const float* k_b      = (const float*)d_in[11];
  const float* v_w      = (const float*)d_in[12];
  const float* v_b      = (const float*)d_in[13];
  const float* o_w      = (const float*)d_in[14];
  const float* o_b      = (const float*)d_in[15];
  const float* mem_vals = (const float*)d_in[16];
  const float* mproj_w  = (const float*)d_in[17];
  const float* mproj_b  = (const float*)d_in[18];
  const float* mattn_w  = (const float*)d_in[19];
  const float* mattn_b  = (const float*)d_in[20];
  const float* rs_w1    = (const float*)d_in[21];
  const float* rs_b1    = (const float*)d_in[22];
  const float* rs_w2    = (const float*)d_in[23];
  const float* rs_b2    = (const float*)d_in[24];
  const float* ln_g     = (const float*)d_in[25];
  const float* ln_b     = (const float*)d_in[26];
  const float* hg_w1    = (const float*)d_in[27];
  const float* hg_b1    = (const float*)d_in[28];
  const float* hg_w2    = (const float*)d_in[29];
  const float* hg_b2    = (const float*)d_in[30];
  const float* integ_w  = (const float*)d_in[31];
  const float* integ_b  = (const float*)d_in[32];

  char* ws = (char*)d_ws;
  auto U = [&](size_t o) { return (unsigned short*)(ws + o); };
  auto F = [&](size_t o) { return (float*)(ws + o); };
  auto I = [&](size_t o) { return (int*)(ws + o); };

  // ---- phase 0: weight transpose+convert ----
  k_tconv<<<dim3(128, 64, 8), 256, 0, stream>>>(moe_w1, U(O_W1T), 2048, 4096, 8388608, 8388608);
  k_tconv<<<dim3(64, 128, 8), 256, 0, stream>>>(moe_w2, U(O_W2T), 4096, 2048, 8388608, 8388608);
  k_tconv4<<<dim3(64, 64, 4), 256, 0, stream>>>(q_w, k_w, v_w, o_w, U(O_QT));
  k_tconv<<<dim3(8, 64, 1), 256, 0, stream>>>(mattn_w, U(O_QT) + (size_t)6144 * 2048, 2048, 256, 0, 0);
  k_tconv<<<dim3(64, 16, 1), 256, 0, stream>>>(mproj_w, U(O_MPT), 512, 2048, 0, 0);
  k_tconv<<<dim3(16, 8, 1), 256, 0, stream>>>(mem_vals, U(O_MVT), 256, 512, 0, 0);
  k_tconv<<<dim3(16, 64, 3), 256, 0, stream>>>(rs_w1, U(O_RH1), 2048, 512, 2048 * 512, 1024 * 2048);
  k_tconv<<<dim3(16, 64, 3), 256, 0, stream>>>(hg_w1, U(O_RH1) + (size_t)512 * 2048, 2048, 512,
                                               2048 * 512, 1024 * 2048);
  k_tconv<<<dim3(64, 16, 3), 256, 0, stream>>>(rs_w2, U(O_RS2), 512, 2048, 512 * 2048, 512 * 2048);
  k_tconv<<<dim3(64, 192, 1), 256, 0, stream>>>(integ_w, U(O_IGT), 6144, 2048, 0, 0);
  k_misc<<<48, 256, 0, stream>>>(mask, F(O_MSK), q_b, k_b, v_b, mattn_b, F(O_QKVB),
                                 rs_b1, hg_b1, F(O_RHB), I(O_META));

  // ---- phase 1: MoE (k_gate also converts h -> XB bf16) ----
  k_gate<<<1024, 256, 0, stream>>>(h, gate_w, gate_b, I(O_META), I(O_E0), I(O_E1),
                                   F(O_W0), F(O_W1), U(O_XB));
  k_buildmap<<<1, 1, 0, stream>>>(I(O_META));
  k_scatter<<<16, 256, 0, stream>>>(I(O_META), I(O_E0), I(O_E1), I(O_S0), I(O_S1), I(O_SRC));

  GArgs z0; memset(&z0, 0, sizeof(z0)); z0.alpha = 1.f; z0.rscale = 1.f;
  {  // MoE GEMM1 with fused token gather (MOE=2)
    GArgs g = z0;
    g.A = U(O_XB); g.lda = 2048;
    g.Bt = U(O_W1T); g.ldb = 2048; g.bSO = (long)4096 * 2048;
    g.N = 4096; g.K = 2048;
    g.adv = moe_b1; g.advSO = 4096;
    g.oB = U(O_H1); g.ldoB = 4096;
    g.meta = I(O_META); g.srcTok = I(O_SRC);
    gemm_bt<2, 1, 0, 0, 1><<<dim3(32, 72, 1), 512, 0, stream>>>(g);
  }
  {
    GArgs g = z0;
    g.A = U(O_H1); g.lda = 4096;
    g.Bt = U(O_W2T); g.ldb = 4096; g.bSO = (long)2048 * 4096;
    g.N = 2048; g.K = 4096;
    g.adv = moe_b2; g.advSO = 2048;
    g.oB = U(O_EO); g.ldoB = 2048;
    g.meta = I(O_META);
    gemm_bt<1, 0, 0, 0, 1><<<dim3(16, 72, 1), 512, 0, stream>>>(g);
  }
  k_combine<<<4096, 256, 0, stream>>>(h, U(O_EO), I(O_S0), I(O_S1), F(O_W0), F(O_W1), U(O_H2B));

  // ---- phase 2: attention ----
  {  // fused qkvm = h2 @ [q_w|k_w|v_w|mattn_w] + biases, [4096][6400]
    GArgs g = z0;
    g.A = U(O_H2B); g.lda = 2048; g.M = 4096; g.N = 6400; g.K = 2048;
    g.Bt = U(O_QT); g.ldb = 2048;
    g.adv = F(O_QKVB);
    g.oB = U(O_QB); g.ldoB = 6400;
    gemm_bt<0, 0, 0, 0, 1><<<dim3(50, 32, 1), 512, 0, stream>>>(g);
  }
  k_tvact<<<dim3(8, 64, 16), 256, 0, stream>>>(U(O_QB), U(O_VT));
  // flash attention v2 (replaces scores GEMM + softmax + PV)
  k_fa<<<dim3(32, 16, 1), 512, 0, stream>>>(U(O_QB), U(O_VT), F(O_MSK), U(O_ATT));
  // memory attention softmax (logits are qkvm cols 6144..6399)
  k_softmax256<<<1024, 256, 0, stream>>>(U(O_QB) + 6144, 6400, U(O_MPB));
  {  // mem_p @ mem_values
    GArgs g = z0;
    g.A = U(O_MPB); g.lda = 256; g.Bt = U(O_MVT); g.ldb = 256;
    g.M = 4096; g.N = 512; g.K = 256;
    g.oB = U(O_MPV); g.ldoB = 512;
    gemm_bt<0, 0, 0, 0, 1><<<dim3(4, 32, 1), 512, 0, stream>>>(g);
  }
  {  // ao2 = attn + 0.3*((mem_p@mem_values)@mem_proj_w + b)
    GArgs g = z0;
    g.A = U(O_MPV); g.lda = 512; g.Bt = U(O_MPT); g.ldb = 512;
    g.M = 4096; g.N = 2048; g.K = 512;
    g.adv = mproj_b;
    g.rB = U(O_ATT); g.ldrB = 2048; g.rscale = 0.3f;
    g.oB = U(O_AO2); g.ldoB = 2048;
    gemm_bt<0, 0, 2, 0, 1><<<dim3(16, 32, 1), 512, 0, stream>>>(g);
  }
  {  // h3 = h2 + ao2 @ o_w + o_b   (bf16 only)
    GArgs g = z0;
    g.A = U(O_AO2); g.lda = 2048; g.Bt = U(O_OT); g.ldb = 2048;
    g.M = 4096; g.N = 2048; g.K = 2048;
    g.adv = o_b;
    g.rB = U(O_H2B); g.ldrB = 2048; g.rscale = 1.f;
    g.oB = U(O_H3B); g.ldoB = 2048;
    gemm_bt<0, 0, 2, 0, 1><<<dim3(16, 32, 1), 512, 0, stream>>>(g);
  }

  // ---- phase 3: hierarchical reasoning (all-bf16 chain) ----
  for (int i = 0; i < 3; i++) {
    const unsigned short* curb = (i == 0) ? U(O_H3B) : U(O_CRB);
    {  // [t1|g1] = relu(cur @ [rs_w1|hg_w1] + [b1|b1]), interleaved [4096][1024]
      GArgs g = z0;
      g.A = curb; g.lda = 2048;
      g.Bt = U(O_RH1) + (size_t)i * 1024 * 2048; g.ldb = 2048;
      g.M = 4096; g.N = 1024; g.K = 2048;
      g.adv = F(O_RHB) + i * 1024;
      g.oB = U(O_T1); g.ldoB = 1024;
      gemm_bt<0, 1, 0, 0, 1><<<dim3(8, 32, 1), 512, 0, stream>>>(g);
    }
    {  // so_pre = t1 @ rs_w2 + b2  (bf16)
      GArgs g = z0;
      g.A = U(O_T1); g.lda = 1024;
      g.Bt = U(O_RS2) + (size_t)i * 2048 * 512; g.ldb = 512;
      g.M = 4096; g.N = 2048; g.K = 512;
      g.adv = rs_b2 + i * 2048;
      g.oB = U(O_SOB); g.ldoB = 2048;
      gemm_bt<0, 0, 0, 0, 1><<<dim3(16, 32, 1), 512, 0, stream>>>(g);
    }
    k_gdot<<<1024, 256, 0, stream>>>(U(O_T1) + 512, 1024, hg_w2 + i * 512, hg_b2 + i, F(O_GV));
    k_lnupdate<<<4096, 256, 0, stream>>>(U(O_SOB), curb, F(O_GV), ln_g + i * 2048,
                                         ln_b + i * 2048, U(O_CRB), U(O_OUS), i);
  }
  {  // out = h3 + concat(outs) @ integ_w + integ_b
    GArgs g = z0;
    g.A = U(O_OUS); g.lda = 6144; g.Bt = U(O_IGT); g.ldb = 6144;
    g.M = 4096; g.N = 2048; g.K = 6144;
    g.adv = integ_b;
    g.rB = U(O_H3B); g.ldrB = 2048; g.rscale = 1.f;
    g.oF = (float*)d_out; g.ldoF = 2048;
    gemm_bt<0, 0, 2, 1, 0><<<dim3(16, 32, 1), 512, 0, stream>>>(g);
  }
}

// Round 18
// 1588.639 us; speedup vs baseline: 1.0991x; 1.0991x over previous
//
#include <hip/hip_runtime.h>
#include <string.h>

// ---------------------------------------------------------------------------
// EnhancedRPTModel: MoE(top-2 routed) + memory-augmented attention + 3-step
// gated reasoning + integration.  bf16 MFMA 16x16x32.
// GEMM engine (R9-proven): 128x128x64, 8 waves, dbuf 64KB LDS (2 blocks/CU),
// STAGE(next) -> ds_read+MFMA(cur) -> vmcnt(0)+barrier; both-sides XOR swizzle.
// MOE=2 fuses token gather.  k_pv fuses softmax+PV with streaming prepass.
// R18: exact revert to R15 (best measured 1589.8us).  Flash-attn variants
// (R16/R17) both lost: HIP __syncthreads drains vmcnt -> 3 forced drains/iter.
// ---------------------------------------------------------------------------

typedef __attribute__((ext_vector_type(4))) float f32x4;
typedef __attribute__((ext_vector_type(8))) __bf16 bf16x8;

#define NTOK 4096            // B*S
#define HDIM 2048
#define AS1 __attribute__((address_space(1)))
#define AS3 __attribute__((address_space(3)))

// ---------------- small helpers ----------------
__device__ __forceinline__ unsigned short f2bf(float f) {
  unsigned u = __float_as_uint(f);
  unsigned r = (u + 0x7fffu + ((u >> 16) & 1u)) >> 16;   // RNE
  return (unsigned short)r;
}
__device__ __forceinline__ float bf2f(unsigned short u) {
  return __uint_as_float(((unsigned)u) << 16);
}
__device__ __forceinline__ void unpack8(uint4 r, float* v) {
  v[0]=bf2f((unsigned short)(r.x&0xffff)); v[1]=bf2f((unsigned short)(r.x>>16));
  v[2]=bf2f((unsigned short)(r.y&0xffff)); v[3]=bf2f((unsigned short)(r.y>>16));
  v[4]=bf2f((unsigned short)(r.z&0xffff)); v[5]=bf2f((unsigned short)(r.z>>16));
  v[6]=bf2f((unsigned short)(r.w&0xffff)); v[7]=bf2f((unsigned short)(r.w>>16));
}
__device__ __forceinline__ uint4 pack8(const float* v) {
  uint4 r;
  r.x = (unsigned)f2bf(v[0]) | ((unsigned)f2bf(v[1])<<16);
  r.y = (unsigned)f2bf(v[2]) | ((unsigned)f2bf(v[3])<<16);
  r.z = (unsigned)f2bf(v[4]) | ((unsigned)f2bf(v[5])<<16);
  r.w = (unsigned)f2bf(v[6]) | ((unsigned)f2bf(v[7])<<16);
  return r;
}

// ---------------- conversion / transpose kernels ----------------
__global__ void k_tconv(const float* __restrict__ in, unsigned short* __restrict__ out,
                        int R, int C, long inB, long outB) {
  __shared__ float tl[32][33];
  const int z = blockIdx.z;
  const float* ip = in + (long)z * inB;
  unsigned short* op = out + (long)z * outB;
  const int tx = threadIdx.x & 31, ty = threadIdx.x >> 5;
  const int c0 = blockIdx.x * 32, r0 = blockIdx.y * 32;
#pragma unroll
  for (int i = 0; i < 4; i++)
    tl[ty + i*8][tx] = ip[(long)(r0 + ty + i*8) * C + c0 + tx];
  __syncthreads();
#pragma unroll
  for (int i = 0; i < 4; i++)
    op[(long)(c0 + ty + i*8) * R + r0 + tx] = f2bf(tl[tx][ty + i*8]);
}

// 4 square 2048x2048 transposes (q_w,k_w,v_w -> slots 0..2; o_w -> after MAT)
__global__ void k_tconv4(const float* __restrict__ i0, const float* __restrict__ i1,
                         const float* __restrict__ i2, const float* __restrict__ i3,
                         unsigned short* __restrict__ out) {
  __shared__ float tl[32][33];
  const int z = blockIdx.z;
  const float* ip = (z == 0) ? i0 : (z == 1) ? i1 : (z == 2) ? i2 : i3;
  unsigned short* op = out + ((z < 3) ? (size_t)z * 2048 * 2048 : (size_t)6400 * 2048);
  const int tx = threadIdx.x & 31, ty = threadIdx.x >> 5;
  const int c0 = blockIdx.x * 32, r0 = blockIdx.y * 32;
#pragma unroll
  for (int i = 0; i < 4; i++)
    tl[ty + i*8][tx] = ip[(long)(r0 + ty + i*8) * 2048 + c0 + tx];
  __syncthreads();
#pragma unroll
  for (int i = 0; i < 4; i++)
    op[(long)(c0 + ty + i*8) * 2048 + r0 + tx] = f2bf(tl[tx][ty + i*8]);
}

// V slice of interleaved qkvm [4096][6400] -> per-(b,h) [256][2048] (d-major)
__global__ void k_tvact(const unsigned short* __restrict__ qkv, unsigned short* __restrict__ vT) {
  __shared__ unsigned short tl[32][33];
  const int z = blockIdx.z, b = z >> 3, hh = z & 7;
  const unsigned short* ip = qkv + (long)b * 2048 * 6400 + 4096 + hh * 256;
  unsigned short* op = vT + (long)z * 256 * 2048;
  const int tx = threadIdx.x & 31, ty = threadIdx.x >> 5;
  const int d0 = blockIdx.x * 32, s0 = blockIdx.y * 32;
#pragma unroll
  for (int i = 0; i < 4; i++)
    tl[ty + i*8][tx] = ip[(long)(s0 + ty + i*8) * 6400 + d0 + tx];
  __syncthreads();
#pragma unroll
  for (int i = 0; i < 4; i++)
    op[(long)(d0 + ty + i*8) * 2048 + s0 + tx] = tl[tx][ty + i*8];
}

// merged small setup: mask vector, qkv|mattn bias concat (6400), rs|hg bias, meta
__global__ void k_misc(const float* __restrict__ mask, float* __restrict__ mv,
                       const float* __restrict__ qb, const float* __restrict__ kb,
                       const float* __restrict__ vb, const float* __restrict__ mb,
                       float* __restrict__ qkvb,
                       const float* __restrict__ rsb1, const float* __restrict__ hgb1,
                       float* __restrict__ rhb, int* __restrict__ meta) {
  const int b = blockIdx.x, t = threadIdx.x;
  if (b < 16) {
    int i = b * 256 + t; mv[i] = -1e9f * mask[i];
  } else if (b < 41) {
    int i = (b - 16) * 256 + t;                         // 0..6399
    if (i < 6400)
      qkvb[i] = (i < 2048) ? qb[i] : (i < 4096) ? kb[i - 2048]
              : (i < 6144) ? vb[i - 4096] : mb[i - 6144];
  } else if (b < 47) {
    int i = (b - 41) * 256 + t;                         // 0..1535
    int s = i >> 9, c = i & 511;
    rhb[s * 1024 + c] = rsb1[i]; rhb[s * 1024 + 512 + c] = hgb1[i];
  } else {
    if (t < 8) meta[t] = 0;
  }
}

// ---------------- routing (h->bf16 conversion fused in) ----------------
__global__ void k_gate(const float* __restrict__ x, const float* __restrict__ gw,
                       const float* __restrict__ gb, int* __restrict__ meta,
                       int* __restrict__ e0a, int* __restrict__ e1a,
                       float* __restrict__ w0a, float* __restrict__ w1a,
                       unsigned short* __restrict__ xb) {
  const int wv = threadIdx.x >> 6, ln = threadIdx.x & 63;
  const int n = blockIdx.x * 4 + wv;
  const float* xr = x + (long)n * HDIM;
  unsigned short* xo = xb + (long)n * HDIM;
  float s[8] = {0,0,0,0,0,0,0,0};
  for (int k = ln; k < HDIM; k += 64) {
    float xv = xr[k];
    xo[k] = f2bf(xv);
    const float* g = gw + (long)k * 8;
#pragma unroll
    for (int e = 0; e < 8; e++) s[e] += xv * g[e];
  }
#pragma unroll
  for (int e = 0; e < 8; e++)
    for (int d = 32; d; d >>= 1) s[e] += __shfl_xor(s[e], d);
  if (ln == 0) {
    float mx = -1e30f;
#pragma unroll
    for (int e = 0; e < 8; e++) { s[e] += gb[e]; mx = fmaxf(mx, s[e]); }
    float p[8], sum = 0.f;
#pragma unroll
    for (int e = 0; e < 8; e++) { p[e] = expf(s[e] - mx); sum += p[e]; }
    float inv = 1.f / sum;
#pragma unroll
    for (int e = 0; e < 8; e++) p[e] *= inv;
    int e0 = 0;
    for (int e = 1; e < 8; e++) if (p[e] > p[e0]) e0 = e;
    int e1 = (e0 == 0) ? 1 : 0;
    for (int e = 0; e < 8; e++) if (e != e0 && p[e] > p[e1]) e1 = e;
    float q = expf(p[e1] - p[e0]);
    float w0 = 1.f / (1.f + q), w1 = q / (1.f + q);
    e0a[n] = e0; e1a[n] = e1; w0a[n] = w0; w1a[n] = w1;
    atomicAdd(&meta[e0], 1); atomicAdd(&meta[e1], 1);
  }
}

__global__ void k_buildmap(int* meta) {        // 128-row tiles
  if (threadIdx.x == 0 && blockIdx.x == 0) {
    int cum = 0, nT = 0;
    for (int e = 0; e < 8; e++) {
      int c = meta[e];
      meta[16 + e] = cum; meta[24 + e] = cum + c; meta[8 + e] = 0;
      int t = (c + 127) >> 7;
      for (int i = 0; i < t; i++) { meta[33 + nT] = e; meta[129 + nT] = cum + i * 128; nT++; }
      cum += c;
    }
    meta[32] = nT;
  }
}

__global__ void k_scatter(int* __restrict__ meta, const int* __restrict__ e0a,
                          const int* __restrict__ e1a, int* __restrict__ s0a,
                          int* __restrict__ s1a, int* __restrict__ srcTok) {
  const int n = blockIdx.x * 256 + threadIdx.x;
  if (n < NTOK) {
    int e0 = e0a[n], e1 = e1a[n];
    int s0 = meta[16 + e0] + atomicAdd(&meta[8 + e0], 1);
    int s1 = meta[16 + e1] + atomicAdd(&meta[8 + e1], 1);
    s0a[n] = s0; s1a[n] = s1; srcTok[s0] = n; srcTok[s1] = n;
  }
}

__global__ void k_combine(const float* __restrict__ h, const unsigned short* __restrict__ eo,
                          const int* __restrict__ s0a, const int* __restrict__ s1a,
                          const float* __restrict__ w0a, const float* __restrict__ w1a,
                          unsigned short* __restrict__ h2b) {
  const int n = blockIdx.x, c = threadIdx.x * 8;
  const float w0 = w0a[n], w1 = w1a[n];
  uint4 a = *(const uint4*)(eo + (long)s0a[n] * HDIM + c);
  uint4 b = *(const uint4*)(eo + (long)s1a[n] * HDIM + c);
  float va[8], vb[8]; unpack8(a, va); unpack8(b, vb);
  const float* hr = h + (long)n * HDIM + c;
  float o[8];
#pragma unroll
  for (int j = 0; j < 8; j++) o[j] = hr[j] + 0.5f * (w0 * va[j] + w1 * vb[j]);
  *(uint4*)(h2b + (long)n * HDIM + c) = pack8(o);
}

// ---------------- softmax (memory attention, 256 wide, bf16 strided in) ----
__global__ void k_softmax256(const unsigned short* __restrict__ in, long ld,
                             unsigned short* __restrict__ out) {
  const int wv = threadIdx.x >> 6, ln = threadIdx.x & 63;
  const long r = (long)blockIdx.x * 4 + wv;
  uint2 raw = ((const uint2*)(in + r * ld))[ln];
  float v[4];
  v[0]=bf2f((unsigned short)(raw.x&0xffff)); v[1]=bf2f((unsigned short)(raw.x>>16));
  v[2]=bf2f((unsigned short)(raw.y&0xffff)); v[3]=bf2f((unsigned short)(raw.y>>16));
  float m = fmaxf(fmaxf(v[0], v[1]), fmaxf(v[2], v[3]));
  for (int d = 32; d; d >>= 1) m = fmaxf(m, __shfl_xor(m, d));
  float s = 0.f;
#pragma unroll
  for (int j = 0; j < 4; j++) { v[j] = expf(v[j] - m); s += v[j]; }
  for (int d = 32; d; d >>= 1) s += __shfl_xor(s, d);
  const float inv = 1.f / s;
  union { unsigned short u[4]; uint2 d2; } p;
#pragma unroll
  for (int j = 0; j < 4; j++) p.u[j] = f2bf(v[j] * inv);
  ((uint2*)(out + r * 256))[ln] = p.d2;
}

// ---------------- reasoning helpers ----------------
__global__ void k_gdot(const unsigned short* __restrict__ g1, long ld, const float* __restrict__ w,
                       const float* __restrict__ bb, float* __restrict__ gv) {
  const int wv = threadIdx.x >> 6, ln = threadIdx.x & 63;
  const int n = blockIdx.x * 4 + wv;
  uint4 raw = *(const uint4*)(g1 + (long)n * ld + ln * 8);
  float v[8]; unpack8(raw, v);
  const float4 wa = ((const float4*)w)[ln * 2];
  const float4 wb = ((const float4*)w)[ln * 2 + 1];
  float s = v[0]*wa.x + v[1]*wa.y + v[2]*wa.z + v[3]*wa.w
          + v[4]*wb.x + v[5]*wb.y + v[6]*wb.z + v[7]*wb.w;
  for (int d = 32; d; d >>= 1) s += __shfl_xor(s, d);
  if (ln == 0) gv[n] = 1.f / (1.f + expf(-(s + bb[0])));
}

__global__ void k_lnupdate(const unsigned short* __restrict__ so,
                           const unsigned short* __restrict__ curIn,
                           const float* __restrict__ gv, const float* __restrict__ lng,
                           const float* __restrict__ lnb,
                           unsigned short* __restrict__ curbOut,
                           unsigned short* __restrict__ outs, int step) {
  const int n = blockIdx.x, t = threadIdx.x, wv = t >> 6, ln = t & 63, c = t * 8;
  uint4 raw = *(const uint4*)(so + (long)n * 2048 + c);
  float x[8]; unpack8(raw, x);
  float s1 = 0.f, s2 = 0.f;
#pragma unroll
  for (int j = 0; j < 8; j++) { s1 += x[j]; s2 += x[j] * x[j]; }
  for (int d = 32; d; d >>= 1) { s1 += __shfl_xor(s1, d); s2 += __shfl_xor(s2, d); }
  __shared__ float a1[4], a2[4];
  if (ln == 0) { a1[wv] = s1; a2[wv] = s2; }
  __syncthreads();
  s1 = a1[0] + a1[1] + a1[2] + a1[3];
  s2 = a2[0] + a2[1] + a2[2] + a2[3];
  const float mean = s1 * (1.f / 2048.f);
  const float var = s2 * (1.f / 2048.f) - mean * mean;
  const float rstd = rsqrtf(var + 1e-5f);
  const float g = gv[n];
  uint4 ci = *(const uint4*)(curIn + (long)n * 2048 + c);
  float cv[8]; unpack8(ci, cv);
  float o[8];
#pragma unroll
  for (int j = 0; j < 8; j++) {
    float l = (x[j] - mean) * rstd * lng[c + j] + lnb[c + j];
    o[j] = cv[j] + g * l;
  }
  const uint4 pk = pack8(o);
  *(uint4*)(curbOut + (long)n * 2048 + c) = pk;
  *(uint4*)(outs + (long)n * 6144 + (long)step * 2048 + c) = pk;
}

// ---------------- GEMM argument block ----------------
struct GArgs {
  const unsigned short* A; long lda, aSO, aSI;
  const unsigned short* Bt; long ldb, bSO, bSI;
  int M, N, K;
  const float* adv; long advSO, advSI;   // per-col addend (bias / -1e9*mask)
  float alpha, rscale;
  const float* rF; long ldrF, rfSO, rfSI;
  const unsigned short* rB; long ldrB, rbSO, rbSI;
  float* oF; long ldoF, ofSO, ofSI;
  unsigned short* oB; long ldoB, obSO, obSI;
  const int* meta;                        // MOE tile map
  const int* srcTok;                      // MOE==2: slot -> token row in A
};

// =============== 128x128x64 dbuf GEMM, 8 waves (2M x 4N) ====================
// Per wave: 64x32 output = acc[4][2].  LDS: 2 buffers x (A 16KB + B 16KB).
// K-step: STAGE(next) | ds_read frags + MFMA(cur) | vmcnt(0)+barrier.
template <int MOE, int RELU, int RESID, int OUTF, int OUTB>
__global__ __launch_bounds__(512) void gemm_bt(GArgs g) {
  __shared__ unsigned short lds[2 * 16384];   // 64 KB
  const int t = threadIdx.x, wv = t >> 6, ln = t & 63, ln15 = ln & 15;
  const int lr8 = ln >> 3;
  const int lsl = (ln & 7) ^ lr8;             // pre-swizzled k-slot (rule #21)
  const int bz = blockIdx.z;
  int row0, rowMax;
  const unsigned short *A, *Bt;
  long advO = 0, rFO = 0, rBO = 0, oFO = 0, oBO = 0;
  if constexpr (MOE) {
    const int ty = blockIdx.y;
    if (ty >= g.meta[32]) return;
    const int e = g.meta[33 + ty];
    row0 = g.meta[129 + ty]; rowMax = g.meta[24 + e];
    A = g.A; Bt = g.Bt + (long)e * g.bSO;
    advO = (long)e * g.advSO;
  } else {
    row0 = blockIdx.y << 7; rowMax = g.M;
    const long bo = (long)(bz >> 3), bi = (long)(bz & 7);
    A = g.A + bo * g.aSO + bi * g.aSI;
    Bt = g.Bt + bo * g.bSO + bi * g.bSI;
    advO = bo * g.advSO + bi * g.advSI;
    rFO = bo * g.rfSO + bi * g.rfSI;
    rBO = bo * g.rbSO + bi * g.rbSI;
    oFO = bo * g.ofSO + bi * g.ofSI;
    oBO = bo * g.obSO + bi * g.obSI;
  }
  const int col0 = blockIdx.x << 7;
  const long lda = g.lda, ldb = g.ldb;
  const int wm = (wv >> 2) << 6;              // 0 / 64
  const int wc = (wv & 3) << 5;               // 0,32,64,96

  int grow0, grow1;
  {
    int r0i = row0 + (wv << 4) + lr8;
    int r1i = r0i + 8;
    if constexpr (MOE) {
      r0i = (r0i < rowMax) ? r0i : (rowMax - 1);
      r1i = (r1i < rowMax) ? r1i : (rowMax - 1);
    }
    if constexpr (MOE == 2) { grow0 = g.srcTok[r0i]; grow1 = g.srcTok[r1i]; }
    else { grow0 = r0i; grow1 = r1i; }
  }

  auto STAGE = [&](int kt, unsigned base) {
    const long kk = ((long)kt << 6) + (lsl << 3);
    {
      const int rb = (wv << 4);
      __builtin_amdgcn_global_load_lds(
          (const AS1 void*)(A + (long)grow0 * lda + kk),
          (AS3 void*)(lds + base + (rb << 6)), 16, 0, 0);
      __builtin_amdgcn_global_load_lds(
          (const AS1 void*)(A + (long)grow1 * lda + kk),
          (AS3 void*)(lds + base + ((rb + 8) << 6)), 16, 0, 0);
    }
#pragma unroll
    for (int l = 0; l < 2; ++l) {
      const int rb = (wv << 4) + (l << 3);
      __builtin_amdgcn_global_load_lds(
          (const AS1 void*)(Bt + (long)(col0 + rb + lr8) * ldb + kk),
          (AS3 void*)(lds + base + 8192 + (rb << 6)), 16, 0, 0);
    }
  };

  const f32x4 fz = {0.f, 0.f, 0.f, 0.f};
  f32x4 acc[4][2];
#pragma unroll
  for (int i = 0; i < 4; i++)
#pragma unroll
    for (int j = 0; j < 2; j++) acc[i][j] = fz;

  const int nt = g.K >> 6;

  STAGE(0, 0);
  asm volatile("s_waitcnt vmcnt(0)" ::: "memory");
  __builtin_amdgcn_s_barrier();

  for (int kt = 0; kt < nt; ++kt) {
    const unsigned aB = (kt & 1) ? 16384u : 0u;
    const unsigned nB = aB ^ 16384u;
    if (kt + 1 < nt) STAGE(kt + 1, nB);
#pragma unroll
    for (int ks = 0; ks < 2; ++ks) {
      const int kb = (ks << 2) + (ln >> 4);
      bf16x8 bg[2];
#pragma unroll
      for (int j = 0; j < 2; ++j) {
        const int r = wc + (j << 4) + ln15;
        bg[j] = *(const bf16x8*)(lds + aB + 8192 + (r << 6) + ((kb ^ (r & 7)) << 3));
      }
      __builtin_amdgcn_s_setprio(1);
#pragma unroll
      for (int i = 0; i < 4; ++i) {
        const int r = wm + (i << 4) + ln15;
        bf16x8 a = *(const bf16x8*)(lds + aB + (r << 6) + ((kb ^ (r & 7)) << 3));
#pragma unroll
        for (int j = 0; j < 2; ++j)
          acc[i][j] = __builtin_amdgcn_mfma_f32_16x16x32_bf16(a, bg[j], acc[i][j], 0, 0, 0);
      }
      __builtin_amdgcn_s_setprio(0);
    }
    asm volatile("s_waitcnt vmcnt(0)" ::: "memory");
    __builtin_amdgcn_s_barrier();
  }

  // epilogue: v = alpha*acc + adv[col];  relu;  v = resid + rscale*v;  store
#pragma unroll
  for (int i = 0; i < 4; i++) {
#pragma unroll
    for (int j = 0; j < 2; j++) {
      const int cc = col0 + wc + (j << 4) + ln15;
      const float av = g.adv ? g.adv[advO + cc] : 0.f;
#pragma unroll
      for (int r = 0; r < 4; r++) {
        const int rr = row0 + wm + (i << 4) + ((ln >> 4) << 2) + r;
        if (rr < rowMax) {
          float v = g.alpha * acc[i][j][r] + av;
          if constexpr (RELU) v = fmaxf(v, 0.f);
          if constexpr (RESID == 1) v = g.rF[rFO + (long)rr * g.ldrF + cc] + g.rscale * v;
          if constexpr (RESID == 2) v = bf2f(g.rB[rBO + (long)rr * g.ldrB + cc]) + g.rscale * v;
          if constexpr (OUTF) g.oF[oFO + (long)rr * g.ldoF + cc] = v;
          if constexpr (OUTB) g.oB[oBO + (long)rr * g.ldoB + cc] = f2bf(v);
        }
      }
    }
  }
}

// ============== fused softmax + PV:  attn = softmax(S) @ V ==================
// (R11/R13-proven)  Block: 64 q-rows x 256 d, 512 threads; streaming prepass.
__global__ __launch_bounds__(512) void k_pv(const unsigned short* __restrict__ S,
                                            const unsigned short* __restrict__ Vt,
                                            unsigned short* __restrict__ O) {
  __shared__ unsigned short lds[4096 + 16384];   // A 64x64 | B 256x64
  __shared__ float pm[64][8], ps[64][8];
  __shared__ float smax[64], sinv[64];
  const int t = threadIdx.x, wv = t >> 6, ln = t & 63, ln15 = ln & 15;
  const int lr8 = ln >> 3, lk = ln & 7;
  const int lsl = lk ^ lr8;                      // pre-swizzled k-slot
  const int rt = blockIdx.x, bh = blockIdx.y;
  const int b = bh >> 3, hh = bh & 7;
  const int row0 = rt << 6;
  const unsigned short* Sb = S + (long)bh * 2048 * 2048;
  const unsigned short* Vb = Vt + (long)bh * 256 * 2048;

  {
    const int r = t >> 3, sg = t & 7;
    const unsigned short* p = Sb + (long)(row0 + r) * 2048 + sg * 256;
    float m = -3.0e38f, s = 0.f;
    for (int i = 0; i < 32; ++i) {
      uint4 raw = ((const uint4*)p)[i];
      float v[8]; unpack8(raw, v);
      float m8 = v[0];
#pragma unroll
      for (int j = 1; j < 8; j++) m8 = fmaxf(m8, v[j]);
      const float mn = fmaxf(m, m8);
      s *= expf(m - mn);
#pragma unroll
      for (int j = 0; j < 8; j++) s += expf(v[j] - mn);
      m = mn;
    }
    pm[r][sg] = m; ps[r][sg] = s;
  }
  __syncthreads();
  if (t < 64) {
    float m = pm[t][0];
#pragma unroll
    for (int j = 1; j < 8; j++) m = fmaxf(m, pm[t][j]);
    float s = 0.f;
#pragma unroll
    for (int j = 0; j < 8; j++) s += ps[t][j] * expf(pm[t][j] - m);
    smax[t] = m; sinv[t] = 1.f / s;
  }
  __syncthreads();
  const int arow = (wv << 3) + lr8;
  const float am = smax[arow], ainv = sinv[arow];

  const f32x4 fz = {0.f, 0.f, 0.f, 0.f};
  f32x4 acc[4][2];
#pragma unroll
  for (int i = 0; i < 4; i++)
#pragma unroll
    for (int j = 0; j < 2; j++) acc[i][j] = fz;

  const int wc = wv << 5;

  for (int kt = 0; kt < 32; ++kt) {
    const long kk = ((long)kt << 6) + (lsl << 3);
    const uint4 araw = *(const uint4*)(Sb + (long)(row0 + arow) * 2048 + kk);
#pragma unroll
    for (int l = 0; l < 4; ++l) {
      const int rb = (l << 6) + (wv << 3);
      __builtin_amdgcn_global_load_lds(
          (const AS1 void*)(Vb + (long)(rb + lr8) * 2048 + kk),
          (AS3 void*)(lds + 4096 + (rb << 6)), 16, 0, 0);
    }
    {
      float v[8]; unpack8(araw, v);
      float pvv[8];
#pragma unroll
      for (int j = 0; j < 8; j++) pvv[j] = expf(v[j] - am) * ainv;
      *(uint4*)(lds + (arow << 6) + (lk << 3)) = pack8(pvv);
    }
    __syncthreads();
#pragma unroll
    for (int ks = 0; ks < 2; ++ks) {
      const int kb = (ks << 2) + (ln >> 4);
      bf16x8 bg[2];
#pragma unroll
      for (int j = 0; j < 2; ++j) {
        const int r = wc + (j << 4) + ln15;
        bg[j] = *(const bf16x8*)(lds + 4096 + (r << 6) + ((kb ^ (r & 7)) << 3));
      }
      __builtin_amdgcn_s_setprio(1);
#pragma unroll
      for (int i = 0; i < 4; ++i) {
        const int r = (i << 4) + ln15;
        bf16x8 a = *(const bf16x8*)(lds + (r << 6) + ((kb ^ (r & 7)) << 3));
#pragma unroll
        for (int j = 0; j < 2; ++j)
          acc[i][j] = __builtin_amdgcn_mfma_f32_16x16x32_bf16(a, bg[j], acc[i][j], 0, 0, 0);
      }
      __builtin_amdgcn_s_setprio(0);
    }
    __syncthreads();
  }

  unsigned short* Ob = O + (long)b * 2048 * 2048 + hh * 256;
#pragma unroll
  for (int i = 0; i < 4; ++i) {
#pragma unroll
    for (int j = 0; j < 2; ++j) {
      const int cc = wc + (j << 4) + ln15;
#pragma unroll
      for (int r = 0; r < 4; ++r) {
        const int rr = row0 + (i << 4) + ((ln >> 4) << 2) + r;
        Ob[(long)rr * 2048 + cc] = f2bf(acc[i][j][r]);
      }
    }
  }
}

// ---------------- workspace layout (bytes) ----------------
static constexpr size_t O_W1T = 0;                                        // [8][4096][2048] bf16
static constexpr size_t O_W2T = O_W1T + (size_t)8 * 4096 * 2048 * 2;      // [8][2048][4096] bf16
static constexpr size_t O_QT  = O_W2T + (size_t)8 * 4096 * 2048 * 2;      // [6400+2048][2048] = Q|K|V|MAT|O
static constexpr size_t O_OT  = O_QT + (size_t)6400 * 2048 * 2;           // o_w^T inside QT block
static constexpr size_t O_MPT = O_QT + (size_t)8448 * 2048 * 2;           // [2048][512]
static constexpr size_t O_MVT = O_MPT + (size_t)2048 * 512 * 2;           // [512][256]
static constexpr size_t O_RH1 = O_MVT + (size_t)512 * 256 * 2;            // [3][1024][2048] rs|hg
static constexpr size_t O_RS2 = O_RH1 + (size_t)3 * 1024 * 2048 * 2;      // [3][2048][512]
static constexpr size_t O_IGT = O_RS2 + (size_t)3 * 2048 * 512 * 2;       // [2048][6144]
static constexpr size_t O_META= O_IGT + (size_t)2048 * 6144 * 2;          // 4KB ints
static constexpr size_t O_E0  = O_META + 4096;
static constexpr size_t O_E1  = O_E0 + 16384;
static constexpr size_t O_W0  = O_E1 + 16384;
static constexpr size_t O_W1  = O_W0 + 16384;
static constexpr size_t O_S0  = O_W1 + 16384;
static constexpr size_t O_S1  = O_S0 + 16384;
static constexpr size_t O_SRC = O_S1 + 16384;                             // 8192 ints
static constexpr size_t O_MSK = O_SRC + 32768;
static constexpr size_t O_GV  = O_MSK + 16384;
static constexpr size_t O_QKVB= O_GV + 16384;                             // 6400 f32
static constexpr size_t O_RHB = O_QKVB + 6400 * 4;                        // 3072 f32
static constexpr size_t O_H2B = O_RHB + 3072 * 4;                         // bf16 [4096][2048]
static constexpr size_t O_H3B = O_H2B + (size_t)4096 * 2048 * 2;
static constexpr size_t O_ATT = O_H3B + (size_t)4096 * 2048 * 2;          // attnb bf16
static constexpr size_t O_AO2 = O_ATT + (size_t)4096 * 2048 * 2;
static constexpr size_t O_MPB = O_AO2 + (size_t)4096 * 2048 * 2;
static constexpr size_t O_MPV = O_MPB + (size_t)4096 * 256 * 2;
static constexpr size_t O_AR  = O_MPV + (size_t)4096 * 512 * 2;           // phase arena
// MoE phase
static constexpr size_t O_XB = O_AR;
static constexpr size_t O_H1 = O_XB + (size_t)4096 * 2048 * 2 + (size_t)8192 * 2048 * 2;
static constexpr size_t O_EO = O_H1 + (size_t)8192 * 4096 * 2;
// attention phase (aliases tail of MoE arena beyond XB): qkvm [4096][6400]
static constexpr size_t O_QB = O_XB + (size_t)4096 * 2048 * 2;
static constexpr size_t O_VT = O_QB + (size_t)4096 * 6400 * 2;
static constexpr size_t O_SC = O_VT + (size_t)4096 * 2048 * 2;            // scores bf16 [16][2048][2048]
// reasoning phase (aliases arena)
static constexpr size_t O_T1 = O_QB;
static constexpr size_t O_SOB= O_T1 + (size_t)4096 * 1024 * 2;            // bf16 [4096][2048]
static constexpr size_t O_CRB= O_SOB + (size_t)4096 * 2048 * 2;
static constexpr size_t O_OUS= O_CRB + (size_t)4096 * 2048 * 2;

extern "C" void kernel_launch(void* const* d_in, const int* in_sizes, int n_in,
                              void* d_out, int out_size, void* d_ws, size_t ws_size,
                              hipStream_t stream) {
  (void)in_sizes; (void)n_in; (void)out_size; (void)ws_size;
  const float* h        = (const float*)d_in[0];
  const float* mask     = (const float*)d_in[1];
  const float* gate_w   = (const float*)d_in[2];
  const float* gate_b   = (const float*)d_in[3];
  const float* moe_w1   = (const float*)d_in[4];
  const float* moe_b1   = (const float*)d_in[5];
  const float* moe_w2   = (const float*)d_in[6];
  const float* moe_b2   = (const float*)d_in[7];
  const float* q_w      = (const float*)d_in[8];
  const float* q_b      = (const float*)d_in[9];
  const float* k_w      = (const float*)d_in[10];
  const float* k_b      = (const float*)d_in[11];
  const float* v_w      = (const float*)d_in[12];
  const float* v_b      = (const float*)d_in[13];
  const float* o_w      = (const float*)d_in[14];
  const float* o_b      = (const float*)d_in[15];
  const float* mem_vals = (const float*)d_in[16];
  const float* mproj_w  = (const float*)d_in[17];
  const float* mproj_b  = (const float*)d_in[18];
  const float* mattn_w  = (const float*)d_in[19];
  const float* mattn_b  = (const float*)d_in[20];
  const float* rs_w1    = (const float*)d_in[21];
  const float* rs_b1    = (const float*)d_in[22];
  const float* rs_w2    = (const float*)d_in[23];
  const float* rs_b2    = (const float*)d_in[24];
  const float* ln_g     = (const float*)d_in[25];
  const float* ln_b     = (const float*)d_in[26];
  const float* hg_w1    = (const float*)d_in[27];
  const float* hg_b1    = (const float*)d_in[28];
  const float* hg_w2    = (const float*)d_in[29];
  const float* hg_b2    = (const float*)d_in[30];
  const float* integ_w  = (const float*)d_in[31];
  const float* integ_b  = (const float*)d_in[32];

  char* ws = (char*)d_ws;
  auto U = [&](size_t o) { return (unsigned short*)(ws + o); };
  auto F = [&](size_t o) { return (float*)(ws + o); };
  auto I = [&](size_t o) { return (int*)(ws + o); };

  // ---- phase 0: weight transpose+convert ----
  k_tconv<<<dim3(128, 64, 8), 256, 0, stream>>>(moe_w1, U(O_W1T), 2048, 4096, 8388608, 8388608);
  k_tconv<<<dim3(64, 128, 8), 256, 0, stream>>>(moe_w2, U(O_W2T), 4096, 2048, 8388608, 8388608);
  k_tconv4<<<dim3(64, 64, 4), 256, 0, stream>>>(q_w, k_w, v_w, o_w, U(O_QT));
  k_tconv<<<dim3(8, 64, 1), 256, 0, stream>>>(mattn_w, U(O_QT) + (size_t)6144 * 2048, 2048, 256, 0, 0);
  k_tconv<<<dim3(64, 16, 1), 256, 0, stream>>>(mproj_w, U(O_MPT), 512, 2048, 0, 0);
  k_tconv<<<dim3(16, 8, 1), 256, 0, stream>>>(mem_vals, U(O_MVT), 256, 512, 0, 0);
  k_tconv<<<dim3(16, 64, 3), 256, 0, stream>>>(rs_w1, U(O_RH1), 2048, 512, 2048 * 512, 1024 * 2048);
  k_tconv<<<dim3(16, 64, 3), 256, 0, stream>>>(hg_w1, U(O_RH1) + (size_t)512 * 2048, 2048, 512,
                                               2048 * 512, 1024 * 2048);
  k_tconv<<<dim3(64, 16, 3), 256, 0, stream>>>(rs_w2, U(O_RS2), 512, 2048, 512 * 2048, 512 * 2048);
  k_tconv<<<dim3(64, 192, 1), 256, 0, stream>>>(integ_w, U(O_IGT), 6144, 2048, 0, 0);
  k_misc<<<48, 256, 0, stream>>>(mask, F(O_MSK), q_b, k_b, v_b, mattn_b, F(O_QKVB),
                                 rs_b1, hg_b1, F(O_RHB), I(O_META));

  // ---- phase 1: MoE (k_gate also converts h -> XB bf16) ----
  k_gate<<<1024, 256, 0, stream>>>(h, gate_w, gate_b, I(O_META), I(O_E0), I(O_E1),
                                   F(O_W0), F(O_W1), U(O_XB));
  k_buildmap<<<1, 1, 0, stream>>>(I(O_META));
  k_scatter<<<16, 256, 0, stream>>>(I(O_META), I(O_E0), I(O_E1), I(O_S0), I(O_S1), I(O_SRC));

  GArgs z0; memset(&z0, 0, sizeof(z0)); z0.alpha = 1.f; z0.rscale = 1.f;
  {  // MoE GEMM1 with fused token gather (MOE=2)
    GArgs g = z0;
    g.A = U(O_XB); g.lda = 2048;
    g.Bt = U(O_W1T); g.ldb = 2048; g.bSO = (long)4096 * 2048;
    g.N = 4096; g.K = 2048;
    g.adv = moe_b1; g.advSO = 4096;
    g.oB = U(O_H1); g.ldoB = 4096;
    g.meta = I(O_META); g.srcTok = I(O_SRC);
    gemm_bt<2, 1, 0, 0, 1><<<dim3(32, 72, 1), 512, 0, stream>>>(g);
  }
  {
    GArgs g = z0;
    g.A = U(O_H1); g.lda = 4096;
    g.Bt = U(O_W2T); g.ldb = 4096; g.bSO = (long)2048 * 4096;
    g.N = 2048; g.K = 4096;
    g.adv = moe_b2; g.advSO = 2048;
    g.oB = U(O_EO); g.ldoB = 2048;
    g.meta = I(O_META);
    gemm_bt<1, 0, 0, 0, 1><<<dim3(16, 72, 1), 512, 0, stream>>>(g);
  }
  k_combine<<<4096, 256, 0, stream>>>(h, U(O_EO), I(O_S0), I(O_S1), F(O_W0), F(O_W1), U(O_H2B));

  // ---- phase 2: attention ----
  {  // fused qkvm = h2 @ [q_w|k_w|v_w|mattn_w] + biases, [4096][6400]
    GArgs g = z0;
    g.A = U(O_H2B); g.lda = 2048; g.M = 4096; g.N = 6400; g.K = 2048;
    g.Bt = U(O_QT); g.ldb = 2048;
    g.adv = F(O_QKVB);
    g.oB = U(O_QB); g.ldoB = 6400;
    gemm_bt<0, 0, 0, 0, 1><<<dim3(50, 32, 1), 512, 0, stream>>>(g);
  }
  k_tvact<<<dim3(8, 64, 16), 256, 0, stream>>>(U(O_QB), U(O_VT));
  {  // scores = QK^T/16 + mask, bf16, per (b,h)
    GArgs g = z0;
    g.A = U(O_QB); g.lda = 6400; g.aSO = (long)2048 * 6400; g.aSI = 256;
    g.Bt = U(O_QB) + 2048; g.ldb = 6400; g.bSO = (long)2048 * 6400; g.bSI = 256;
    g.M = 2048; g.N = 2048; g.K = 256;
    g.adv = F(O_MSK); g.advSO = 2048; g.advSI = 0;
    g.alpha = 0.0625f;
    g.oB = U(O_SC); g.ldoB = 2048; g.obSO = 33554432; g.obSI = 4194304;
    gemm_bt<0, 0, 0, 0, 1><<<dim3(16, 16, 16), 512, 0, stream>>>(g);
  }
  // fused softmax + PV (streaming prepass)
  k_pv<<<dim3(32, 16, 1), 512, 0, stream>>>(U(O_SC), U(O_VT), U(O_ATT));
  // memory attention softmax (logits are qkvm cols 6144..6399)
  k_softmax256<<<1024, 256, 0, stream>>>(U(O_QB) + 6144, 6400, U(O_MPB));
  {  // mem_p @ mem_values
    GArgs g = z0;
    g.A = U(O_MPB); g.lda = 256; g.Bt = U(O_MVT); g.ldb = 256;
    g.M = 4096; g.N = 512; g.K = 256;
    g.oB = U(O_MPV); g.ldoB = 512;
    gemm_bt<0, 0, 0, 0, 1><<<dim3(4, 32, 1), 512, 0, stream>>>(g);
  }
  {  // ao2 = attn + 0.3*((mem_p@mem_values)@mem_proj_w + b)
    GArgs g = z0;
    g.A = U(O_MPV); g.lda = 512; g.Bt = U(O_MPT); g.ldb = 512;
    g.M = 4096; g.N = 2048; g.K = 512;
    g.adv = mproj_b;
    g.rB = U(O_ATT); g.ldrB = 2048; g.rscale = 0.3f;
    g.oB = U(O_AO2); g.ldoB = 2048;
    gemm_bt<0, 0, 2, 0, 1><<<dim3(16, 32, 1), 512, 0, stream>>>(g);
  }
  {  // h3 = h2 + ao2 @ o_w + o_b   (bf16 only)
    GArgs g = z0;
    g.A = U(O_AO2); g.lda = 2048; g.Bt = U(O_OT); g.ldb = 2048;
    g.M = 4096; g.N = 2048; g.K = 2048;
    g.adv = o_b;
    g.rB = U(O_H2B); g.ldrB = 2048; g.rscale = 1.f;
    g.oB = U(O_H3B); g.ldoB = 2048;
    gemm_bt<0, 0, 2, 0, 1><<<dim3(16, 32, 1), 512, 0, stream>>>(g);
  }

  // ---- phase 3: hierarchical reasoning (all-bf16 chain) ----
  for (int i = 0; i < 3; i++) {
    const unsigned short* curb = (i == 0) ? U(O_H3B) : U(O_CRB);
    {  // [t1|g1] = relu(cur @ [rs_w1|hg_w1] + [b1|b1]), interleaved [4096][1024]
      GArgs g = z0;
      g.A = curb; g.lda = 2048;
      g.Bt = U(O_RH1) + (size_t)i * 1024 * 2048; g.ldb = 2048;
      g.M = 4096; g.N = 1024; g.K = 2048;
      g.adv = F(O_RHB) + i * 1024;
      g.oB = U(O_T1); g.ldoB = 1024;
      gemm_bt<0, 1, 0, 0, 1><<<dim3(8, 32, 1), 512, 0, stream>>>(g);
    }
    {  // so_pre = t1 @ rs_w2 + b2  (bf16)
      GArgs g = z0;
      g.A = U(O_T1); g.lda = 1024;
      g.Bt = U(O_RS2) + (size_t)i * 2048 * 512; g.ldb = 512;
      g.M = 4096; g.N = 2048; g.K = 512;
      g.adv = rs_b2 + i * 2048;
      g.oB = U(O_SOB); g.ldoB = 2048;
      gemm_bt<0, 0, 0, 0, 1><<<dim3(16, 32, 1), 512, 0, stream>>>(g);
    }
    k_gdot<<<1024, 256, 0, stream>>>(U(O_T1) + 512, 1024, hg_w2 + i * 512, hg_b2 + i, F(O_GV));
    k_lnupdate<<<4096, 256, 0, stream>>>(U(O_SOB), curb, F(O_GV), ln_g + i * 2048,
                                         ln_b + i * 2048, U(O_CRB), U(O_OUS), i);
  }
  {  // out = h3 + concat(outs) @ integ_w + integ_b
    GArgs g = z0;
    g.A = U(O_OUS); g.lda = 6144; g.Bt = U(O_IGT); g.ldb = 6144;
    g.M = 4096; g.N = 2048; g.K = 6144;
    g.adv = integ_b;
    g.rB = U(O_H3B); g.ldrB = 2048; g.rscale = 1.f;
    g.oF = (float*)d_out; g.ldoF = 2048;
    gemm_bt<0, 0, 2, 1, 0><<<dim3(16, 32, 1), 512, 0, stream>>>(g);
  }
}